// Round 1
// baseline (330.454 us; speedup 1.0000x reference)
//
#include <hip/hip_runtime.h>
#include <math.h>

#define NPTS 87296
#define NCLS 16
#define KPOS 256
#define KHN  2048
#define NBLK 341            // NPTS / 256 exactly
#define PI_F   3.14159265358979323846f
#define HPI_F  1.57079632679489661923f

struct InPtrs { const float* p[40]; };
// input index = pre*20 + lvl*4 + {cls:0, box:1, ang:2, ctr:3}; pre: t=0, s=1

// ---------------- persistent device scratch (rewritten every call) ----------------
__device__ float g_max_vals[NPTS];
__device__ float g_sig_tiou[NPTS];
__device__ float g_sig_cls_max[NPTS];
__device__ int   g_class_ind[NPTS];
__device__ int   g_pos_mask[NPTS];
__device__ int   g_hn_mask[NPTS];
__device__ float g_loc_targets[NPTS * 5];
__device__ float g_loc_mask[NPTS];
__device__ int   g_pidx[KPOS];
__device__ int   g_pvalid[KPOS];
__device__ float g_pv[KPOS];
__device__ int   g_hidx[KHN];
__device__ int   g_hvalid[KHN];
__device__ float g_pos_bbox[KPOS * 5];
__device__ float g_pos_cor[KPOS * 8];
__device__ float g_pos_area[KPOS];
__device__ float g_pos_scale[KPOS];
__device__ int   g_pos_class[KPOS];
__device__ float g_hn_px[KHN];
__device__ float g_hn_py[KHN];
__device__ float g_hn_cor[KHN * 8];
__device__ float g_hn_area[KHN];
__device__ float g_hn_scale[KHN];
__device__ int   g_hn_class[KHN];
__device__ float g_agg[KHN * 5];
__device__ int   g_potential[KHN];
__device__ float g_partials[NBLK * 6];

// ---------------- helpers ----------------
__device__ __forceinline__ float sigmoidf(float x) {
  if (x >= 0.f) return 1.f / (1.f + expf(-x));
  float e = expf(x);
  return e / (1.f + e);
}
__device__ __forceinline__ float crs(float ax, float ay, float bx, float by) {
  return ax * by - ay * bx;
}
__device__ __forceinline__ float mod_pos(float x, float y) {
  float r = fmodf(x, y);
  if (r < 0.f) r += y;
  return r;
}
__device__ __forceinline__ void point_info(int n, int& lvl, int& idx, int& hw,
                                           float& px, float& py) {
  int off, wsh; float stride;
  if (n < 65536)      { lvl = 0; off = 0;     wsh = 8; stride = 8.f;   hw = 65536; }
  else if (n < 81920) { lvl = 1; off = 65536; wsh = 7; stride = 16.f;  hw = 16384; }
  else if (n < 86016) { lvl = 2; off = 81920; wsh = 6; stride = 32.f;  hw = 4096; }
  else if (n < 87040) { lvl = 3; off = 86016; wsh = 5; stride = 64.f;  hw = 1024; }
  else                { lvl = 4; off = 87040; wsh = 4; stride = 128.f; hw = 256; }
  idx = n - off;
  int y = idx >> wsh, x = idx & ((1 << wsh) - 1);
  px = ((float)x + 0.5f) * stride;
  py = ((float)y + 0.5f) * stride;
}

// ---------------- kernel 1: per-point teacher stats ----------------
__global__ __launch_bounds__(256) void k_prep(InPtrs P) {
  int n = blockIdx.x * 256 + threadIdx.x;
  if (n >= NPTS) return;
  int lvl, idx, hw; float px, py;
  point_info(n, lvl, idx, hw, px, py);
  const float* cls = P.p[lvl * 4 + 0];
  const float* ctr = P.p[lvl * 4 + 3];
  float stiou = sigmoidf(ctr[idx]);
  float mv = -1.f, scm = 0.f; int ci = 0;
  for (int c = 0; c < NCLS; c++) {
    float sc = sigmoidf(cls[c * hw + idx]);
    if (sc > scm) scm = sc;
    float j = sc * stiou;
    if (j > mv) { mv = j; ci = c; }
  }
  g_max_vals[n] = mv;
  g_class_ind[n] = ci;
  g_sig_tiou[n] = stiou;
  g_sig_cls_max[n] = scm;
}

// ---------------- kernel 2: control (stats, threshold, masks, top-k) ----------------
#define MASK_ALL 0
#define MASK_POS 1
#define MASK_HN  2
__device__ __forceinline__ int sel_mask(int mode, int n) {
  return mode == MASK_ALL ? 1 : (mode == MASK_POS ? g_pos_mask[n] : g_hn_mask[n]);
}
__device__ __forceinline__ unsigned sel_key(int n) {
  return __float_as_uint(g_max_vals[n]);   // max_vals > 0 -> monotonic as uint
}

__device__ void radix_select(int mode, int K, int* out_idx, int* out_valid, float* out_val,
                             int* hist, int* scan_a, int* scan_b, int* sh) {
  int tid = threadIdx.x;
  // total masked count
  int c = 0;
  for (int n = tid; n < NPTS; n += 1024) if (sel_mask(mode, n)) c++;
  scan_a[tid] = c; __syncthreads();
  for (int st = 512; st > 0; st >>= 1) {
    if (tid < st) scan_a[tid] += scan_a[tid + st];
    __syncthreads();
  }
  int total = scan_a[0];
  __syncthreads();

  unsigned kth = 0u;
  if (total > K) {
    unsigned prefix = 0; int rem = K;
    for (int pass = 0; pass < 4; pass++) {
      int shift = 24 - 8 * pass;
      if (tid < 256) hist[tid] = 0;
      __syncthreads();
      for (int n = tid; n < NPTS; n += 1024) {
        if (sel_mask(mode, n)) {
          unsigned k = sel_key(n);
          if (pass == 0 || ((k >> (shift + 8)) == prefix))
            atomicAdd(&hist[(k >> shift) & 255], 1);
        }
      }
      __syncthreads();
      if (tid == 0) {
        int cum = 0, b = 255;
        for (; b > 0; b--) {
          if (cum + hist[b] >= rem) break;
          cum += hist[b];
        }
        sh[0] = (int)((prefix << 8) | (unsigned)b);
        sh[1] = rem - cum;
      }
      __syncthreads();
      prefix = (unsigned)sh[0]; rem = sh[1];
      __syncthreads();
    }
    kth = prefix;
  }

  // deterministic chunked compaction (index-ordered, matches top_k tie-break)
  const int chunk = (NPTS + 1023) / 1024;
  int start = tid * chunk; if (start > NPTS) start = NPTS;
  int end = start + chunk; if (end > NPTS) end = NPTS;
  int cgt = 0, ceq = 0;
  for (int n = start; n < end; n++) {
    if (sel_mask(mode, n)) {
      unsigned k = sel_key(n);
      if (k > kth) cgt++;
      else if (k == kth) ceq++;
    }
  }
  scan_a[tid] = cgt; scan_b[tid] = ceq; __syncthreads();
  if (tid == 0) {
    int ag = 0, ae = 0;
    for (int i = 0; i < 1024; i++) {
      int tg = scan_a[i], te = scan_b[i];
      scan_a[i] = ag; scan_b[i] = ae;
      ag += tg; ae += te;
    }
    sh[0] = ag; sh[1] = ae;
  }
  __syncthreads();
  int cnt_gt = sh[0], cnt_eq = sh[1];
  int og = scan_a[tid], oe = cnt_gt + scan_b[tid];
  for (int n = start; n < end; n++) {
    if (sel_mask(mode, n)) {
      unsigned k = sel_key(n);
      if (k > kth) {
        out_idx[og] = n; out_valid[og] = 1;
        if (out_val) out_val[og] = g_max_vals[n];
        og++;
      } else if (k == kth) {
        if (oe < K) {
          out_idx[oe] = n; out_valid[oe] = 1;
          if (out_val) out_val[oe] = g_max_vals[n];
        }
        oe++;
      }
    }
  }
  int kmc = K - cnt_gt;
  int used = cnt_gt + (cnt_eq < kmc ? cnt_eq : kmc);
  __syncthreads();
  for (int i = used + tid; i < K; i += 1024) {
    out_idx[i] = 0; out_valid[i] = 0;
    if (out_val) out_val[i] = -1.f;
  }
  __syncthreads();
}

__global__ __launch_bounds__(1024) void k_control() {
  __shared__ float sfred[1024];
  __shared__ int   sired[1024];
  __shared__ int   hist[256];
  __shared__ int   scan_a[1024];
  __shared__ int   scan_b[1024];
  __shared__ float sh_f[4];
  __shared__ int   sh_i[8];
  int tid = threadIdx.x;

  // ---- mean over candidates (max_vals >= 0.1)
  float s = 0.f; int c = 0;
  for (int n = tid; n < NPTS; n += 1024) {
    float v = g_max_vals[n];
    if (v >= 0.1f) { s += v; c++; }
  }
  sfred[tid] = s; sired[tid] = c; __syncthreads();
  for (int st = 512; st > 0; st >>= 1) {
    if (tid < st) { sfred[tid] += sfred[tid + st]; sired[tid] += sired[tid + st]; }
    __syncthreads();
  }
  if (tid == 0) {
    sh_i[0] = sired[0];
    int d = sired[0] > 1 ? sired[0] : 1;
    sh_f[0] = sfred[0] / (float)d;
  }
  __syncthreads();
  int ncand = sh_i[0]; float mean = sh_f[0];

  // ---- unbiased variance, pos threshold
  s = 0.f;
  for (int n = tid; n < NPTS; n += 1024) {
    float v = g_max_vals[n];
    if (v >= 0.1f) { float d = v - mean; s += d * d; }
  }
  __syncthreads();
  sfred[tid] = s; __syncthreads();
  for (int st = 512; st > 0; st >>= 1) {
    if (tid < st) sfred[tid] += sfred[tid + st];
    __syncthreads();
  }
  if (tid == 0) {
    int d = (ncand - 1) > 1 ? (ncand - 1) : 1;
    float var = sfred[0] / (float)d;
    float th = fminf(mean + sqrtf(var), 0.4f);
    if (ncand == 0) th = __int_as_float(0x7f800000);  // +inf
    sh_f[1] = th;
  }
  __syncthreads();
  float thresh = sh_f[1];

  // ---- raw positive count
  c = 0;
  for (int n = tid; n < NPTS; n += 1024) if (g_max_vals[n] >= thresh) c++;
  sired[tid] = c; __syncthreads();
  for (int st = 512; st > 0; st >>= 1) {
    if (tid < st) sired[tid] += sired[tid + st];
    __syncthreads();
  }
  if (tid == 0) sh_i[1] = sired[0];
  __syncthreads();
  int fallback = (sh_i[1] == 0);

  // ---- masks
  for (int n = tid; n < NPTS; n += 1024) {
    float v = g_max_vals[n];
    g_pos_mask[n] = (!fallback && v >= thresh) ? 1 : 0;
    g_hn_mask[n]  = (v >= 0.1f && v < thresh) ? 1 : 0;
  }
  __syncthreads();

  if (fallback) {  // top-10 over ALL points becomes the positive mask
    radix_select(MASK_ALL, 10, g_pidx, g_pvalid, g_pv, hist, scan_a, scan_b, &sh_i[2]);
    for (int i = tid; i < 10; i += 1024)
      if (g_pvalid[i]) g_pos_mask[g_pidx[i]] = 1;
    __syncthreads();
  }
  radix_select(MASK_POS, KPOS, g_pidx, g_pvalid, g_pv, hist, scan_a, scan_b, &sh_i[2]);
  radix_select(MASK_HN,  KHN,  g_hidx, g_hvalid, (float*)0, hist, scan_a, scan_b, &sh_i[2]);
}

// ---------------- kernel 3: decode selected boxes ----------------
__device__ void decode_box(int n, const InPtrs& P, float* bb, float* cor,
                           float& area, float& scale, int& cls_out,
                           float* opx, float* opy) {
  int lvl, idx, hw; float px, py;
  point_info(n, lvl, idx, hw, px, py);
  const float* box = P.p[lvl * 4 + 1];
  const float* ang = P.p[lvl * 4 + 2];
  float l = box[idx], t = box[hw + idx], r = box[2 * hw + idx], b = box[3 * hw + idx];
  float a = ang[idx];
  float ca = cosf(a), sa = sinf(a);
  float w = l + r, h = t + b;
  float oxl = (r - l) * 0.5f, oyl = (b - t) * 0.5f;
  float ox = ca * oxl - sa * oyl;
  float oy = sa * oxl + ca * oyl;
  float an = mod_pos(a + HPI_F, PI_F) - HPI_F;
  float cx = px + ox, cy = py + oy;
  bb[0] = cx; bb[1] = cy; bb[2] = w; bb[3] = h; bb[4] = an;
  float c2 = cosf(an), s2 = sinf(an);
  const float dxs[4] = {-0.5f, 0.5f, 0.5f, -0.5f};
  const float dys[4] = {-0.5f, -0.5f, 0.5f, 0.5f};
#pragma unroll
  for (int k = 0; k < 4; k++) {
    float dx = dxs[k] * w, dy = dys[k] * h;
    cor[2 * k]     = cx + dx * c2 - dy * s2;
    cor[2 * k + 1] = cy + dx * s2 + dy * c2;
  }
  area = fabsf(w * h);
  scale = (float)lvl;
  cls_out = g_class_ind[n];
  if (opx) { *opx = px; *opy = py; }
}

__global__ __launch_bounds__(256) void k_decode(InPtrs P) {
  int i = blockIdx.x * 256 + threadIdx.x;
  if (i < KPOS) {
    float bb[5] = {0,0,0,0,0}, cor[8] = {0,0,0,0,0,0,0,0};
    float ar = 0.f, sc = 0.f; int cl = 0;
    if (g_pvalid[i]) decode_box(g_pidx[i], P, bb, cor, ar, sc, cl, (float*)0, (float*)0);
#pragma unroll
    for (int k = 0; k < 5; k++) g_pos_bbox[i * 5 + k] = bb[k];
#pragma unroll
    for (int k = 0; k < 8; k++) g_pos_cor[i * 8 + k] = cor[k];
    g_pos_area[i] = ar; g_pos_scale[i] = sc; g_pos_class[i] = cl;
  } else if (i < KPOS + KHN) {
    int h = i - KPOS;
    float bb[5] = {0,0,0,0,0}, cor[8] = {0,0,0,0,0,0,0,0};
    float ar = 0.f, sc = 0.f, px = 0.f, py = 0.f; int cl = 0;
    if (g_hvalid[h]) decode_box(g_hidx[h], P, bb, cor, ar, sc, cl, &px, &py);
#pragma unroll
    for (int k = 0; k < 8; k++) g_hn_cor[h * 8 + k] = cor[k];
    g_hn_area[h] = ar; g_hn_scale[h] = sc; g_hn_class[h] = cl;
    g_hn_px[h] = px; g_hn_py[h] = py;
  }
}

// ---------------- convex quad intersection (faithful to reference) ----------------
__device__ float inter_area(const float* __restrict__ A, const float* __restrict__ B) {
  float ax[4], ay[4], bx[4], by[4];
#pragma unroll
  for (int i = 0; i < 4; i++) {
    ax[i] = A[2 * i]; ay[i] = A[2 * i + 1];
    bx[i] = B[2 * i]; by[i] = B[2 * i + 1];
  }
  float dax[4], day[4], dbx[4], dby[4];
#pragma unroll
  for (int i = 0; i < 4; i++) {
    int i1 = (i + 1) & 3;
    dax[i] = ax[i1] - ax[i]; day[i] = ay[i1] - ay[i];
    dbx[i] = bx[i1] - bx[i]; dby[i] = by[i1] - by[i];
  }
  float px[24], py[24]; bool val[24];
#pragma unroll
  for (int i = 0; i < 4; i++) {
#pragma unroll
    for (int j = 0; j < 4; j++) {
      float dx = bx[j] - ax[i], dy = by[j] - ay[i];
      float den = crs(dax[i], day[i], dbx[j], dby[j]);
      float ad = fabsf(den);
      float ds = (ad < 1e-10f) ? 1.0f : den;
      float t = crs(dx, dy, dbx[j], dby[j]) / ds;
      float u = crs(dx, dy, dax[i], day[i]) / ds;
      bool ok = (ad > 1e-10f) & (t >= 0.f) & (t <= 1.f) & (u >= 0.f) & (u <= 1.f);
      int k = i * 4 + j;
      px[k] = ax[i] + t * dax[i];
      py[k] = ay[i] + t * day[i];
      val[k] = ok;
    }
  }
#pragma unroll
  for (int i = 0; i < 4; i++) {   // corners of A inside B
    bool ge = true, le = true;
#pragma unroll
    for (int j = 0; j < 4; j++) {
      float s = crs(dbx[j], dby[j], ax[i] - bx[j], ay[i] - by[j]);
      ge = ge && (s >= -1e-9f);
      le = le && (s <= 1e-9f);
    }
    val[16 + i] = ge || le; px[16 + i] = ax[i]; py[16 + i] = ay[i];
  }
#pragma unroll
  for (int j = 0; j < 4; j++) {   // corners of B inside A
    bool ge = true, le = true;
#pragma unroll
    for (int i = 0; i < 4; i++) {
      float s = crs(dax[i], day[i], bx[j] - ax[i], by[j] - ay[i]);
      ge = ge && (s >= -1e-9f);
      le = le && (s <= 1e-9f);
    }
    val[20 + j] = ge || le; px[20 + j] = bx[j]; py[20 + j] = by[j];
  }
  int n = 0; float sx = 0.f, sy = 0.f;
#pragma unroll
  for (int k = 0; k < 24; k++) if (val[k]) { n++; sx += px[k]; sy += py[k]; }
  float dn = (float)(n > 1 ? n : 1);
  float cx = sx / dn, cy = sy / dn;
  float ang[24];
#pragma unroll
  for (int k = 0; k < 24; k++) {
    if (!val[k]) { px[k] = cx; py[k] = cy; }
    ang[k] = atan2f(py[k] - cy, px[k] - cx);
  }
  // stable insertion sort by angle (ties keep original index order)
  int ord[24];
  for (int k = 0; k < 24; k++) ord[k] = k;
  for (int k = 1; k < 24; k++) {
    int o = ord[k]; float a = ang[o]; int m = k - 1;
    while (m >= 0 && ang[ord[m]] > a) { ord[m + 1] = ord[m]; m--; }
    ord[m + 1] = o;
  }
  float s2 = 0.f;
  for (int k = 0; k < 24; k++) {
    int i0 = ord[k];
    int i1 = ord[(k + 1) % 24];
    s2 += crs(px[i0] - cx, py[i0] - cy, px[i1] - cx, py[i1] - cy);
  }
  float area = 0.5f * fabsf(s2);
  return (n >= 3) ? area : 0.f;
}

// ---------------- kernel 4: IoU + weighted aggregation per hard negative ----------------
__global__ __launch_bounds__(256) void k_iou() {
  int h = blockIdx.x;
  int j = threadIdx.x;
  if (!g_hvalid[h]) {
    if (j == 0) g_potential[h] = 0;
    return;
  }
  float wsum = 0.f, wb[5] = {0,0,0,0,0}, anyv = 0.f;
  if (g_pvalid[j]) {
    // cheap flags first
    bool valid = (g_pos_class[j] == g_hn_class[h]) &&
                 (fabsf(g_pos_scale[j] - g_hn_scale[h]) <= 1.0f);
    if (valid) {
      float cx = g_pos_bbox[j * 5 + 0], cy = g_pos_bbox[j * 5 + 1];
      float bw = g_pos_bbox[j * 5 + 2], bh = g_pos_bbox[j * 5 + 3];
      float an = g_pos_bbox[j * 5 + 4];
      float ca = cosf(an), sa = sinf(an);
      float dx = g_hn_px[h] - cx, dy = g_hn_py[h] - cy;
      float ox = ca * dx + sa * dy, oy = -sa * dx + ca * dy;
      float m = fminf(fminf(bw * 0.5f + ox, bw * 0.5f - ox),
                      fminf(bh * 0.5f + oy, bh * 0.5f - oy));
      valid = (m > 0.f);
    }
    if (valid) {
      float inter = inter_area(&g_hn_cor[h * 8], &g_pos_cor[j * 8]);
      float iou = inter / (g_hn_area[h] + g_pos_area[j] - inter + 1e-8f);
      valid = (iou >= 0.6f);
    }
    if (valid) {
      anyv = 1.f;
      float w = g_pv[j];
      wsum = w;
#pragma unroll
      for (int k = 0; k < 5; k++) wb[k] = w * g_pos_bbox[j * 5 + k];
    }
  }
  __shared__ float red[256][8];
  red[j][0] = wsum;
#pragma unroll
  for (int k = 0; k < 5; k++) red[j][1 + k] = wb[k];
  red[j][6] = anyv;
  __syncthreads();
  for (int st = 128; st > 0; st >>= 1) {
    if (j < st)
#pragma unroll
      for (int k = 0; k < 7; k++) red[j][k] += red[j + st][k];
    __syncthreads();
  }
  if (j == 0) {
    int pot = red[0][6] > 0.f;
    g_potential[h] = pot;
    if (pot) {
      float inv = 1.f / fmaxf(red[0][0], 1e-8f);
      float bb[5];
#pragma unroll
      for (int k = 0; k < 5; k++) bb[k] = red[0][1 + k] * inv;
      float ca = cosf(bb[4]), sa = sinf(bb[4]);
      float dx = g_hn_px[h] - bb[0], dy = g_hn_py[h] - bb[1];
      float ox = ca * dx + sa * dy, oy = -sa * dx + ca * dy;
      g_agg[h * 5 + 0] = bb[2] * 0.5f + ox;
      g_agg[h * 5 + 1] = bb[3] * 0.5f + oy;
      g_agg[h * 5 + 2] = bb[2] * 0.5f - ox;
      g_agg[h * 5 + 3] = bb[3] * 0.5f - oy;
      g_agg[h * 5 + 4] = bb[4];
    }
  }
}

// ---------------- kernel 5: base loc targets ----------------
__global__ __launch_bounds__(256) void k_base(InPtrs P) {
  int n = blockIdx.x * 256 + threadIdx.x;
  if (n >= NPTS) return;
  int pm = g_pos_mask[n];
  float v[5] = {0,0,0,0,0};
  if (pm) {
    int lvl, idx, hw; float px, py;
    point_info(n, lvl, idx, hw, px, py);
    const float* box = P.p[lvl * 4 + 1];
    const float* ang = P.p[lvl * 4 + 2];
    v[0] = box[idx]; v[1] = box[hw + idx];
    v[2] = box[2 * hw + idx]; v[3] = box[3 * hw + idx];
    v[4] = ang[idx];
  }
#pragma unroll
  for (int k = 0; k < 5; k++) g_loc_targets[n * 5 + k] = v[k];
  g_loc_mask[n] = pm ? 1.f : 0.f;
}

// ---------------- kernel 6: scatter aggregated targets ----------------
__global__ __launch_bounds__(256) void k_scatter() {
  int h = blockIdx.x * 256 + threadIdx.x;
  if (h >= KHN) return;
  if (g_potential[h]) {
    int n = g_hidx[h];
#pragma unroll
    for (int k = 0; k < 5; k++) g_loc_targets[n * 5 + k] = g_agg[h * 5 + k];
    g_loc_mask[n] = 1.f;
  }
}

// ---------------- kernel 7: per-point losses -> block partials ----------------
__global__ __launch_bounds__(256) void k_loss(InPtrs P) {
  int tid = threadIdx.x;
  int n = blockIdx.x * 256 + tid;
  float v0, v1, v2, v3, v4, v5;
  {
    int lvl, idx, hw; float px, py;
    point_info(n, lvl, idx, hw, px, py);
    int pm = g_pos_mask[n], hm = g_hn_mask[n];
    int sel = pm | hm;
    bool lp = g_loc_mask[n] > 0.f;
    float ctmax = sel ? g_sig_cls_max[n] : 0.f;
    const float* tcls = P.p[lvl * 4 + 0];
    const float* scls = P.p[20 + lvl * 4 + 0];
    const float* sbox = P.p[20 + lvl * 4 + 1];
    const float* sang = P.p[20 + lvl * 4 + 2];
    const float* sctr = P.p[20 + lvl * 4 + 3];
    float siou = sigmoidf(sctr[idx]);
    float scl = 0.f;
    for (int c = 0; c < NCLS; c++) {
      float jc = sigmoidf(scls[c * hw + idx]) * siou;
      float ct = sel ? sigmoidf(tcls[c * hw + idx]) : 0.f;
      float p = jc;
      if (p < 1e-12f) p = 1e-12f;
      float pu = 1.f - 1e-12f;
      if (p > pu) p = pu;
      float bce = -(ct * logf(p) + (1.f - ct) * log1pf(-p));
      float d = fabsf(jc - ct);
      scl += bce * d * d;
    }
    v0 = scl;
    float lw = lp ? ctmax : 0.f;
    float sb = 0.f;
#pragma unroll
    for (int k = 0; k < 5; k++) {
      float sv = (k < 4) ? sbox[k * hw + idx] : sang[idx];
      float d = fabsf(sv - g_loc_targets[n * 5 + k]);
      sb += (d < 1.f) ? 0.5f * d * d : d - 0.5f;
    }
    v1 = sb * lw;
    v2 = 0.f;
    if (lp) {
      float p = siou;
      if (p < 1e-12f) p = 1e-12f;
      float pu = 1.f - 1e-12f;
      if (p > pu) p = pu;
      float ti = g_sig_tiou[n];
      v2 = -(ti * logf(p) + (1.f - ti) * log1pf(-p));
    }
    v3 = pm ? ctmax : 0.f;   // cls_avg
    v4 = lw;                 // loc_avg
    v5 = lp ? 1.f : 0.f;     // iou_avg
  }
  __shared__ float red[256][6];
  red[tid][0] = v0; red[tid][1] = v1; red[tid][2] = v2;
  red[tid][3] = v3; red[tid][4] = v4; red[tid][5] = v5;
  __syncthreads();
  for (int st = 128; st > 0; st >>= 1) {
    if (tid < st)
#pragma unroll
      for (int k = 0; k < 6; k++) red[tid][k] += red[tid + st][k];
    __syncthreads();
  }
  if (tid == 0)
#pragma unroll
    for (int k = 0; k < 6; k++) g_partials[blockIdx.x * 6 + k] = red[0][k];
}

// ---------------- kernel 8: final reduce ----------------
__global__ __launch_bounds__(256) void k_final(float* out) {
  int tid = threadIdx.x;
  float a[6] = {0,0,0,0,0,0};
  for (int b = tid; b < NBLK; b += 256)
#pragma unroll
    for (int k = 0; k < 6; k++) a[k] += g_partials[b * 6 + k];
  __shared__ float red[256][6];
#pragma unroll
  for (int k = 0; k < 6; k++) red[tid][k] = a[k];
  __syncthreads();
  for (int st = 128; st > 0; st >>= 1) {
    if (tid < st)
#pragma unroll
      for (int k = 0; k < 6; k++) red[tid][k] += red[tid + st][k];
    __syncthreads();
  }
  if (tid == 0) {
    out[0] = red[0][0] / fmaxf(red[0][3], 1e-8f);
    out[1] = red[0][1] / fmaxf(red[0][4], 1e-8f);
    out[2] = red[0][2] / fmaxf(red[0][5], 1.f);
  }
}

extern "C" void kernel_launch(void* const* d_in, const int* in_sizes, int n_in,
                              void* d_out, int out_size, void* d_ws, size_t ws_size,
                              hipStream_t stream) {
  (void)in_sizes; (void)n_in; (void)out_size; (void)d_ws; (void)ws_size;
  InPtrs P;
  for (int i = 0; i < 40; i++) P.p[i] = (const float*)d_in[i];
  k_prep<<<NBLK, 256, 0, stream>>>(P);
  k_control<<<1, 1024, 0, stream>>>();
  k_decode<<<(KPOS + KHN) / 256, 256, 0, stream>>>(P);
  k_iou<<<KHN, 256, 0, stream>>>();
  k_base<<<NBLK, 256, 0, stream>>>(P);
  k_scatter<<<KHN / 256, 256, 0, stream>>>();
  k_loss<<<NBLK, 256, 0, stream>>>(P);
  k_final<<<1, 256, 0, stream>>>((float*)d_out);
}

// Round 2
// 87.073 us; speedup vs baseline: 3.7951x; 3.7951x over previous
//
#include <hip/hip_runtime.h>
#include <math.h>

#define NPTS 87296
#define NCLS 16
#define KPOS 256
#define KHN  2048
#define NBLK 341            // NPTS / 256 exactly
#define CAP  4096           // compacted-candidate capacity (slow path beyond)
#define PI_F   3.14159265358979323846f
#define HPI_F  1.57079632679489661923f

struct InPtrs { const float* p[40]; };
// input index = pre*20 + lvl*4 + {cls:0, box:1, ang:2, ctr:3}; pre: t=0, s=1

// ---------------- persistent device scratch (rewritten every call) ----------------
__device__ float g_max_vals[NPTS];
__device__ float g_sig_tiou[NPTS];
__device__ float g_sig_cls_max[NPTS];
__device__ int   g_class_ind[NPTS];
__device__ int   g_pos_mask[NPTS];
__device__ int   g_hn_mask[NPTS];
__device__ int   g_hnflag[NPTS];          // 1 = loc target overridden by aggregated hn
__device__ float g_loc_targets[NPTS * 5]; // only hn slots are written/read
__device__ float g_bsum[NBLK];
__device__ float g_bsumsq[NBLK];
__device__ int   g_bcnt[NBLK];
__device__ int   g_bpos[NBLK];
__device__ int   g_bhn[NBLK];
__device__ int   g_pos_off[NBLK];
__device__ int   g_hn_off[NBLK];
__device__ float g_thresh;
__device__ int   g_total_pos;
__device__ int   g_total_hn;
__device__ int   g_fallback;
__device__ int   g_pos_cand[CAP];
__device__ int   g_hn_cand[CAP];
__device__ int   g_pidx[KPOS];
__device__ int   g_pvalid[KPOS];
__device__ float g_pv[KPOS];
__device__ int   g_hidx[KHN];
__device__ int   g_hvalid[KHN];
__device__ float g_pos_bbox[KPOS * 5];
__device__ float g_pos_cor[KPOS * 8];
__device__ float g_pos_area[KPOS];
__device__ float g_pos_scale[KPOS];
__device__ int   g_pos_class[KPOS];
__device__ float g_hn_px[KHN];
__device__ float g_hn_py[KHN];
__device__ float g_hn_cor[KHN * 8];
__device__ float g_hn_area[KHN];
__device__ float g_hn_scale[KHN];
__device__ int   g_hn_class[KHN];
__device__ float g_agg[KHN * 5];
__device__ int   g_potential[KHN];
__device__ float g_partials[NBLK * 6];

// ---------------- helpers ----------------
__device__ __forceinline__ float sigmoidf(float x) {
  if (x >= 0.f) return 1.f / (1.f + expf(-x));
  float e = expf(x);
  return e / (1.f + e);
}
__device__ __forceinline__ float crs(float ax, float ay, float bx, float by) {
  return ax * by - ay * bx;
}
__device__ __forceinline__ float mod_pos(float x, float y) {
  float r = fmodf(x, y);
  if (r < 0.f) r += y;
  return r;
}
__device__ __forceinline__ void point_info(int n, int& lvl, int& idx, int& hw,
                                           float& px, float& py) {
  int off, wsh; float stride;
  if (n < 65536)      { lvl = 0; off = 0;     wsh = 8; stride = 8.f;   hw = 65536; }
  else if (n < 81920) { lvl = 1; off = 65536; wsh = 7; stride = 16.f;  hw = 16384; }
  else if (n < 86016) { lvl = 2; off = 81920; wsh = 6; stride = 32.f;  hw = 4096; }
  else if (n < 87040) { lvl = 3; off = 86016; wsh = 5; stride = 64.f;  hw = 1024; }
  else                { lvl = 4; off = 87040; wsh = 4; stride = 128.f; hw = 256; }
  idx = n - off;
  int y = idx >> wsh, x = idx & ((1 << wsh) - 1);
  px = ((float)x + 0.5f) * stride;
  py = ((float)y + 0.5f) * stride;
}

// ---------------- kernel 1: per-point teacher stats + mean/var partials ----------------
__global__ __launch_bounds__(256) void k_prep(InPtrs P) {
  int tid = threadIdx.x;
  int n = blockIdx.x * 256 + tid;
  int lvl, idx, hw; float px, py;
  point_info(n, lvl, idx, hw, px, py);
  const float* cls = P.p[lvl * 4 + 0];
  const float* ctr = P.p[lvl * 4 + 3];
  float stiou = sigmoidf(ctr[idx]);
  float mv = -1.f, scm = 0.f; int ci = 0;
  for (int c = 0; c < NCLS; c++) {
    float sc = sigmoidf(cls[c * hw + idx]);
    if (sc > scm) scm = sc;
    float j = sc * stiou;
    if (j > mv) { mv = j; ci = c; }
  }
  g_max_vals[n] = mv;
  g_class_ind[n] = ci;
  g_sig_tiou[n] = stiou;
  g_sig_cls_max[n] = scm;
  g_hnflag[n] = 0;
  // block partials for candidate mean/var
  float isc = (mv >= 0.1f) ? 1.f : 0.f;
  __shared__ float r0[256], r1[256], r2[256];
  r0[tid] = isc; r1[tid] = isc * mv; r2[tid] = isc * mv * mv;
  __syncthreads();
  for (int st = 128; st > 0; st >>= 1) {
    if (tid < st) { r0[tid] += r0[tid + st]; r1[tid] += r1[tid + st]; r2[tid] += r2[tid + st]; }
    __syncthreads();
  }
  if (tid == 0) {
    g_bcnt[blockIdx.x] = (int)r0[0];
    g_bsum[blockIdx.x] = r1[0];
    g_bsumsq[blockIdx.x] = r2[0];
  }
}

// ---------------- kernel 2: threshold from partials ----------------
__global__ __launch_bounds__(512) void k_thresh() {
  int tid = threadIdx.x;
  __shared__ float s1[512], s2[512];
  __shared__ int   s0[512];
  int c = 0; float s = 0.f, q = 0.f;
  for (int b = tid; b < NBLK; b += 512) { c += g_bcnt[b]; s += g_bsum[b]; q += g_bsumsq[b]; }
  s0[tid] = c; s1[tid] = s; s2[tid] = q; __syncthreads();
  for (int st = 256; st > 0; st >>= 1) {
    if (tid < st) { s0[tid] += s0[tid + st]; s1[tid] += s1[tid + st]; s2[tid] += s2[tid + st]; }
    __syncthreads();
  }
  if (tid == 0) {
    int n = s0[0]; float sum = s1[0], sumsq = s2[0];
    float mean = sum / (float)(n > 1 ? n : 1);
    float E = sumsq - 2.f * mean * sum + (float)n * mean * mean;
    if (E < 0.f) E = 0.f;
    float var = E / (float)((n - 1) > 1 ? (n - 1) : 1);
    float th = fminf(mean + sqrtf(var), 0.4f);
    if (n == 0) th = __int_as_float(0x7f800000);  // +inf
    g_thresh = th;
  }
}

// ---------------- kernel 3: masks + per-block counts ----------------
__global__ __launch_bounds__(256) void k_mask() {
  int tid = threadIdx.x;
  int n = blockIdx.x * 256 + tid;
  float th = g_thresh;
  float v = g_max_vals[n];
  int pm = (v >= th) ? 1 : 0;
  int hm = (v >= 0.1f && v < th) ? 1 : 0;
  g_pos_mask[n] = pm; g_hn_mask[n] = hm;
  __shared__ int r0[256], r1[256];
  r0[tid] = pm; r1[tid] = hm; __syncthreads();
  for (int st = 128; st > 0; st >>= 1) {
    if (tid < st) { r0[tid] += r0[tid + st]; r1[tid] += r1[tid + st]; }
    __syncthreads();
  }
  if (tid == 0) { g_bpos[blockIdx.x] = r0[0]; g_bhn[blockIdx.x] = r1[0]; }
}

// ---------------- kernel 4: scan block counts -> offsets, totals, fallback flag ----------------
__global__ __launch_bounds__(512) void k_scan() {
  int tid = threadIdx.x;
  __shared__ int sp[512], sh_[512];
  int vp = (tid < NBLK) ? g_bpos[tid] : 0;
  int vh = (tid < NBLK) ? g_bhn[tid] : 0;
  sp[tid] = vp; sh_[tid] = vh; __syncthreads();
  for (int off = 1; off < 512; off <<= 1) {
    int ap = (tid >= off) ? sp[tid - off] : 0;
    int ah = (tid >= off) ? sh_[tid - off] : 0;
    __syncthreads();
    sp[tid] += ap; sh_[tid] += ah;
    __syncthreads();
  }
  if (tid < NBLK) { g_pos_off[tid] = sp[tid] - vp; g_hn_off[tid] = sh_[tid] - vh; }
  if (tid == 0) {
    g_total_pos = sp[511];
    g_total_hn = sh_[511];
    g_fallback = (sp[511] == 0) ? 1 : 0;
  }
}

// ---------------- kernel 5: deterministic index-ordered compaction ----------------
__global__ __launch_bounds__(256) void k_compact() {
  int tid = threadIdx.x;
  int b = blockIdx.x;
  int n = b * 256 + tid;
  int pm = g_pos_mask[n], hm = g_hn_mask[n];
  __shared__ int sp[256], sh_[256];
  sp[tid] = pm; sh_[tid] = hm; __syncthreads();
  for (int off = 1; off < 256; off <<= 1) {
    int ap = (tid >= off) ? sp[tid - off] : 0;
    int ah = (tid >= off) ? sh_[tid - off] : 0;
    __syncthreads();
    sp[tid] += ap; sh_[tid] += ah;
    __syncthreads();
  }
  if (pm) {
    int o = g_pos_off[b] + sp[tid] - pm;
    if (o < CAP) g_pos_cand[o] = n;
  }
  if (hm) {
    int o = g_hn_off[b] + sh_[tid] - hm;
    if (o < CAP) g_hn_cand[o] = n;
  }
}

// ---------------- radix select paths (rare) ----------------
#define MASK_ALL 0
#define MASK_POS 1
#define MASK_HN  2
__device__ __forceinline__ int sel_mask(int mode, int n) {
  return mode == MASK_ALL ? 1 : (mode == MASK_POS ? g_pos_mask[n] : g_hn_mask[n]);
}

__device__ void radix_select_mask(int mode, int K, int* out_idx, int* out_valid, float* out_val,
                                  int* hist, int* scan_a, int* scan_b, int* sh) {
  int tid = threadIdx.x;
  int c = 0;
  for (int n = tid; n < NPTS; n += 1024) if (sel_mask(mode, n)) c++;
  scan_a[tid] = c; __syncthreads();
  for (int st = 512; st > 0; st >>= 1) {
    if (tid < st) scan_a[tid] += scan_a[tid + st];
    __syncthreads();
  }
  int total = scan_a[0];
  __syncthreads();

  unsigned kth = 0u;
  if (total > K) {
    unsigned prefix = 0; int rem = K;
    for (int pass = 0; pass < 4; pass++) {
      int shift = 24 - 8 * pass;
      if (tid < 256) hist[tid] = 0;
      __syncthreads();
      for (int n = tid; n < NPTS; n += 1024) {
        if (sel_mask(mode, n)) {
          unsigned k = __float_as_uint(g_max_vals[n]);
          if (pass == 0 || ((k >> (shift + 8)) == prefix))
            atomicAdd(&hist[(k >> shift) & 255], 1);
        }
      }
      __syncthreads();
      if (tid == 0) {
        int cum = 0, b = 255;
        for (; b > 0; b--) {
          if (cum + hist[b] >= rem) break;
          cum += hist[b];
        }
        sh[0] = (int)((prefix << 8) | (unsigned)b);
        sh[1] = rem - cum;
      }
      __syncthreads();
      prefix = (unsigned)sh[0]; rem = sh[1];
      __syncthreads();
    }
    kth = prefix;
  }

  const int chunk = (NPTS + 1023) / 1024;
  int start = tid * chunk; if (start > NPTS) start = NPTS;
  int end = start + chunk; if (end > NPTS) end = NPTS;
  int cgt = 0, ceq = 0;
  for (int n = start; n < end; n++) {
    if (sel_mask(mode, n)) {
      unsigned k = __float_as_uint(g_max_vals[n]);
      if (k > kth) cgt++;
      else if (k == kth) ceq++;
    }
  }
  scan_a[tid] = cgt; scan_b[tid] = ceq; __syncthreads();
  if (tid == 0) {
    int ag = 0, ae = 0;
    for (int i = 0; i < 1024; i++) {
      int tg = scan_a[i], te = scan_b[i];
      scan_a[i] = ag; scan_b[i] = ae;
      ag += tg; ae += te;
    }
    sh[0] = ag; sh[1] = ae;
  }
  __syncthreads();
  int cnt_gt = sh[0], cnt_eq = sh[1];
  int og = scan_a[tid], oe = cnt_gt + scan_b[tid];
  for (int n = start; n < end; n++) {
    if (sel_mask(mode, n)) {
      unsigned k = __float_as_uint(g_max_vals[n]);
      if (k > kth) {
        out_idx[og] = n; out_valid[og] = 1;
        if (out_val) out_val[og] = g_max_vals[n];
        og++;
      } else if (k == kth) {
        if (oe < K) {
          out_idx[oe] = n; out_valid[oe] = 1;
          if (out_val) out_val[oe] = g_max_vals[n];
        }
        oe++;
      }
    }
  }
  int kmc = K - cnt_gt;
  int used = cnt_gt + (cnt_eq < kmc ? cnt_eq : kmc);
  __syncthreads();
  for (int i = used + tid; i < K; i += 1024) {
    out_idx[i] = 0; out_valid[i] = 0;
    if (out_val) out_val[i] = -1.f;
  }
  __syncthreads();
}

__device__ void radix_select_list(const int* list, int count, int K,
                                  int* out_idx, int* out_valid, float* out_val,
                                  int* hist, int* scan_a, int* scan_b, int* sh) {
  // requires count > K
  int tid = threadIdx.x;
  unsigned prefix = 0; int rem = K;
  for (int pass = 0; pass < 4; pass++) {
    int shift = 24 - 8 * pass;
    if (tid < 256) hist[tid] = 0;
    __syncthreads();
    for (int i = tid; i < count; i += 1024) {
      unsigned k = __float_as_uint(g_max_vals[list[i]]);
      if (pass == 0 || ((k >> (shift + 8)) == prefix))
        atomicAdd(&hist[(k >> shift) & 255], 1);
    }
    __syncthreads();
    if (tid == 0) {
      int cum = 0, b = 255;
      for (; b > 0; b--) {
        if (cum + hist[b] >= rem) break;
        cum += hist[b];
      }
      sh[0] = (int)((prefix << 8) | (unsigned)b);
      sh[1] = rem - cum;
    }
    __syncthreads();
    prefix = (unsigned)sh[0]; rem = sh[1];
    __syncthreads();
  }
  unsigned kth = prefix;
  int chunk = (count + 1023) / 1024;
  int start = tid * chunk; if (start > count) start = count;
  int end = start + chunk; if (end > count) end = count;
  int cgt = 0, ceq = 0;
  for (int i = start; i < end; i++) {
    unsigned k = __float_as_uint(g_max_vals[list[i]]);
    if (k > kth) cgt++;
    else if (k == kth) ceq++;
  }
  scan_a[tid] = cgt; scan_b[tid] = ceq; __syncthreads();
  if (tid == 0) {
    int ag = 0, ae = 0;
    for (int i = 0; i < 1024; i++) {
      int tg = scan_a[i], te = scan_b[i];
      scan_a[i] = ag; scan_b[i] = ae;
      ag += tg; ae += te;
    }
    sh[0] = ag;
  }
  __syncthreads();
  int cnt_gt = sh[0];
  int og = scan_a[tid], oe = cnt_gt + scan_b[tid];
  for (int i = start; i < end; i++) {
    int n = list[i];
    unsigned k = __float_as_uint(g_max_vals[n]);
    if (k > kth) {
      out_idx[og] = n; out_valid[og] = 1;
      if (out_val) out_val[og] = g_max_vals[n];
      og++;
    } else if (k == kth) {
      if (oe < K) {
        out_idx[oe] = n; out_valid[oe] = 1;
        if (out_val) out_val[oe] = g_max_vals[n];
      }
      oe++;
    }
  }
  __syncthreads();
}

// ---------------- kernel 6: selection (fast copy path; radix only when needed) ----------------
__global__ __launch_bounds__(1024) void k_select() {
  int tid = threadIdx.x;
  __shared__ int hist[256], scan_a[1024], scan_b[1024], sh_i[4];
  int fallback = g_fallback;
  int tp = g_total_pos, thn = g_total_hn;

  if (!fallback && tp <= KPOS) {
    for (int i = tid; i < KPOS; i += 1024) {
      if (i < tp) {
        int n = g_pos_cand[i];
        g_pidx[i] = n; g_pvalid[i] = 1; g_pv[i] = g_max_vals[n];
      } else { g_pidx[i] = 0; g_pvalid[i] = 0; g_pv[i] = -1.f; }
    }
  } else if (!fallback && tp <= CAP) {
    radix_select_list(g_pos_cand, tp, KPOS, g_pidx, g_pvalid, g_pv, hist, scan_a, scan_b, sh_i);
  } else if (!fallback) {
    radix_select_mask(MASK_POS, KPOS, g_pidx, g_pvalid, g_pv, hist, scan_a, scan_b, sh_i);
  } else {
    // fallback: top-10 over all points becomes the positive set
    radix_select_mask(MASK_ALL, 10, g_pidx, g_pvalid, g_pv, hist, scan_a, scan_b, sh_i);
    for (int i = tid; i < 10; i += 1024)
      if (g_pvalid[i]) g_pos_mask[g_pidx[i]] = 1;
    for (int i = 10 + tid; i < KPOS; i += 1024) {
      g_pidx[i] = 0; g_pvalid[i] = 0; g_pv[i] = -1.f;
    }
  }
  __syncthreads();

  if (thn <= KHN) {
    for (int i = tid; i < KHN; i += 1024) {
      if (i < thn) { g_hidx[i] = g_hn_cand[i]; g_hvalid[i] = 1; }
      else { g_hidx[i] = 0; g_hvalid[i] = 0; }
    }
  } else if (thn <= CAP) {
    radix_select_list(g_hn_cand, thn, KHN, g_hidx, g_hvalid, (float*)0, hist, scan_a, scan_b, sh_i);
  } else {
    radix_select_mask(MASK_HN, KHN, g_hidx, g_hvalid, (float*)0, hist, scan_a, scan_b, sh_i);
  }
}

// ---------------- kernel 7: decode selected boxes ----------------
__device__ void decode_box(int n, const InPtrs& P, float* bb, float* cor,
                           float& area, float& scale, int& cls_out,
                           float* opx, float* opy) {
  int lvl, idx, hw; float px, py;
  point_info(n, lvl, idx, hw, px, py);
  const float* box = P.p[lvl * 4 + 1];
  const float* ang = P.p[lvl * 4 + 2];
  float l = box[idx], t = box[hw + idx], r = box[2 * hw + idx], b = box[3 * hw + idx];
  float a = ang[idx];
  float ca = cosf(a), sa = sinf(a);
  float w = l + r, h = t + b;
  float oxl = (r - l) * 0.5f, oyl = (b - t) * 0.5f;
  float ox = ca * oxl - sa * oyl;
  float oy = sa * oxl + ca * oyl;
  float an = mod_pos(a + HPI_F, PI_F) - HPI_F;
  float cx = px + ox, cy = py + oy;
  bb[0] = cx; bb[1] = cy; bb[2] = w; bb[3] = h; bb[4] = an;
  float c2 = cosf(an), s2 = sinf(an);
  const float dxs[4] = {-0.5f, 0.5f, 0.5f, -0.5f};
  const float dys[4] = {-0.5f, -0.5f, 0.5f, 0.5f};
#pragma unroll
  for (int k = 0; k < 4; k++) {
    float dx = dxs[k] * w, dy = dys[k] * h;
    cor[2 * k]     = cx + dx * c2 - dy * s2;
    cor[2 * k + 1] = cy + dx * s2 + dy * c2;
  }
  area = fabsf(w * h);
  scale = (float)lvl;
  cls_out = g_class_ind[n];
  if (opx) { *opx = px; *opy = py; }
}

__global__ __launch_bounds__(256) void k_decode(InPtrs P) {
  int i = blockIdx.x * 256 + threadIdx.x;
  if (i < KPOS) {
    float bb[5] = {0,0,0,0,0}, cor[8] = {0,0,0,0,0,0,0,0};
    float ar = 0.f, sc = 0.f; int cl = 0;
    if (g_pvalid[i]) decode_box(g_pidx[i], P, bb, cor, ar, sc, cl, (float*)0, (float*)0);
#pragma unroll
    for (int k = 0; k < 5; k++) g_pos_bbox[i * 5 + k] = bb[k];
#pragma unroll
    for (int k = 0; k < 8; k++) g_pos_cor[i * 8 + k] = cor[k];
    g_pos_area[i] = ar; g_pos_scale[i] = sc; g_pos_class[i] = cl;
  } else if (i < KPOS + KHN) {
    int h = i - KPOS;
    float bb[5] = {0,0,0,0,0}, cor[8] = {0,0,0,0,0,0,0,0};
    float ar = 0.f, sc = 0.f, px = 0.f, py = 0.f; int cl = 0;
    if (g_hvalid[h]) decode_box(g_hidx[h], P, bb, cor, ar, sc, cl, &px, &py);
#pragma unroll
    for (int k = 0; k < 8; k++) g_hn_cor[h * 8 + k] = cor[k];
    g_hn_area[h] = ar; g_hn_scale[h] = sc; g_hn_class[h] = cl;
    g_hn_px[h] = px; g_hn_py[h] = py;
  }
}

// ---------------- convex quad intersection (faithful to reference) ----------------
__device__ float inter_area(const float* __restrict__ A, const float* __restrict__ B) {
  float ax[4], ay[4], bx[4], by[4];
#pragma unroll
  for (int i = 0; i < 4; i++) {
    ax[i] = A[2 * i]; ay[i] = A[2 * i + 1];
    bx[i] = B[2 * i]; by[i] = B[2 * i + 1];
  }
  float dax[4], day[4], dbx[4], dby[4];
#pragma unroll
  for (int i = 0; i < 4; i++) {
    int i1 = (i + 1) & 3;
    dax[i] = ax[i1] - ax[i]; day[i] = ay[i1] - ay[i];
    dbx[i] = bx[i1] - bx[i]; dby[i] = by[i1] - by[i];
  }
  float px[24], py[24]; bool val[24];
#pragma unroll
  for (int i = 0; i < 4; i++) {
#pragma unroll
    for (int j = 0; j < 4; j++) {
      float dx = bx[j] - ax[i], dy = by[j] - ay[i];
      float den = crs(dax[i], day[i], dbx[j], dby[j]);
      float ad = fabsf(den);
      float ds = (ad < 1e-10f) ? 1.0f : den;
      float t = crs(dx, dy, dbx[j], dby[j]) / ds;
      float u = crs(dx, dy, dax[i], day[i]) / ds;
      bool ok = (ad > 1e-10f) & (t >= 0.f) & (t <= 1.f) & (u >= 0.f) & (u <= 1.f);
      int k = i * 4 + j;
      px[k] = ax[i] + t * dax[i];
      py[k] = ay[i] + t * day[i];
      val[k] = ok;
    }
  }
#pragma unroll
  for (int i = 0; i < 4; i++) {   // corners of A inside B
    bool ge = true, le = true;
#pragma unroll
    for (int j = 0; j < 4; j++) {
      float s = crs(dbx[j], dby[j], ax[i] - bx[j], ay[i] - by[j]);
      ge = ge && (s >= -1e-9f);
      le = le && (s <= 1e-9f);
    }
    val[16 + i] = ge || le; px[16 + i] = ax[i]; py[16 + i] = ay[i];
  }
#pragma unroll
  for (int j = 0; j < 4; j++) {   // corners of B inside A
    bool ge = true, le = true;
#pragma unroll
    for (int i = 0; i < 4; i++) {
      float s = crs(dax[i], day[i], bx[j] - ax[i], by[j] - ay[i]);
      ge = ge && (s >= -1e-9f);
      le = le && (s <= 1e-9f);
    }
    val[20 + j] = ge || le; px[20 + j] = bx[j]; py[20 + j] = by[j];
  }
  int n = 0; float sx = 0.f, sy = 0.f;
#pragma unroll
  for (int k = 0; k < 24; k++) if (val[k]) { n++; sx += px[k]; sy += py[k]; }
  float dn = (float)(n > 1 ? n : 1);
  float cx = sx / dn, cy = sy / dn;
  float ang[24];
#pragma unroll
  for (int k = 0; k < 24; k++) {
    if (!val[k]) { px[k] = cx; py[k] = cy; }
    ang[k] = atan2f(py[k] - cy, px[k] - cx);
  }
  int ord[24];
  for (int k = 0; k < 24; k++) ord[k] = k;
  for (int k = 1; k < 24; k++) {
    int o = ord[k]; float a = ang[o]; int m = k - 1;
    while (m >= 0 && ang[ord[m]] > a) { ord[m + 1] = ord[m]; m--; }
    ord[m + 1] = o;
  }
  float s2 = 0.f;
  for (int k = 0; k < 24; k++) {
    int i0 = ord[k];
    int i1 = ord[(k + 1) % 24];
    s2 += crs(px[i0] - cx, py[i0] - cy, px[i1] - cx, py[i1] - cy);
  }
  float area = 0.5f * fabsf(s2);
  return (n >= 3) ? area : 0.f;
}

// ---------------- kernel 8: IoU + weighted aggregation per hard negative ----------------
__global__ __launch_bounds__(256) void k_iou() {
  int h = blockIdx.x;
  int j = threadIdx.x;
  if (!g_hvalid[h]) {
    if (j == 0) g_potential[h] = 0;
    return;
  }
  float wsum = 0.f, wb[5] = {0,0,0,0,0}, anyv = 0.f;
  if (g_pvalid[j]) {
    bool valid = (g_pos_class[j] == g_hn_class[h]) &&
                 (fabsf(g_pos_scale[j] - g_hn_scale[h]) <= 1.0f);
    if (valid) {
      float cx = g_pos_bbox[j * 5 + 0], cy = g_pos_bbox[j * 5 + 1];
      float bw = g_pos_bbox[j * 5 + 2], bh = g_pos_bbox[j * 5 + 3];
      float an = g_pos_bbox[j * 5 + 4];
      float ca = cosf(an), sa = sinf(an);
      float dx = g_hn_px[h] - cx, dy = g_hn_py[h] - cy;
      float ox = ca * dx + sa * dy, oy = -sa * dx + ca * dy;
      float m = fminf(fminf(bw * 0.5f + ox, bw * 0.5f - ox),
                      fminf(bh * 0.5f + oy, bh * 0.5f - oy));
      valid = (m > 0.f);
    }
    if (valid) {
      float inter = inter_area(&g_hn_cor[h * 8], &g_pos_cor[j * 8]);
      float iou = inter / (g_hn_area[h] + g_pos_area[j] - inter + 1e-8f);
      valid = (iou >= 0.6f);
    }
    if (valid) {
      anyv = 1.f;
      float w = g_pv[j];
      wsum = w;
#pragma unroll
      for (int k = 0; k < 5; k++) wb[k] = w * g_pos_bbox[j * 5 + k];
    }
  }
  __shared__ float red[256][8];
  red[j][0] = wsum;
#pragma unroll
  for (int k = 0; k < 5; k++) red[j][1 + k] = wb[k];
  red[j][6] = anyv;
  __syncthreads();
  for (int st = 128; st > 0; st >>= 1) {
    if (j < st)
#pragma unroll
      for (int k = 0; k < 7; k++) red[j][k] += red[j + st][k];
    __syncthreads();
  }
  if (j == 0) {
    int pot = red[0][6] > 0.f;
    g_potential[h] = pot;
    if (pot) {
      float inv = 1.f / fmaxf(red[0][0], 1e-8f);
      float bb[5];
#pragma unroll
      for (int k = 0; k < 5; k++) bb[k] = red[0][1 + k] * inv;
      float ca = cosf(bb[4]), sa = sinf(bb[4]);
      float dx = g_hn_px[h] - bb[0], dy = g_hn_py[h] - bb[1];
      float ox = ca * dx + sa * dy, oy = -sa * dx + ca * dy;
      g_agg[h * 5 + 0] = bb[2] * 0.5f + ox;
      g_agg[h * 5 + 1] = bb[3] * 0.5f + oy;
      g_agg[h * 5 + 2] = bb[2] * 0.5f - ox;
      g_agg[h * 5 + 3] = bb[3] * 0.5f - oy;
      g_agg[h * 5 + 4] = bb[4];
    }
  }
}

// ---------------- kernel 9: scatter aggregated targets ----------------
__global__ __launch_bounds__(256) void k_scatter() {
  int h = blockIdx.x * 256 + threadIdx.x;
  if (h >= KHN) return;
  if (g_hvalid[h] && g_potential[h]) {
    int n = g_hidx[h];
#pragma unroll
    for (int k = 0; k < 5; k++) g_loc_targets[n * 5 + k] = g_agg[h * 5 + k];
    g_hnflag[n] = 1;
  }
}

// ---------------- kernel 10: per-point losses -> block partials ----------------
__global__ __launch_bounds__(256) void k_loss(InPtrs P) {
  int tid = threadIdx.x;
  int n = blockIdx.x * 256 + tid;
  float v0, v1, v2, v3, v4, v5;
  {
    int lvl, idx, hw; float px, py;
    point_info(n, lvl, idx, hw, px, py);
    int pm = g_pos_mask[n], hm = g_hn_mask[n], hf = g_hnflag[n];
    int sel = pm | hm;
    bool lp = (pm | hf) != 0;
    float ctmax = sel ? g_sig_cls_max[n] : 0.f;
    const float* tcls = P.p[lvl * 4 + 0];
    const float* tbox = P.p[lvl * 4 + 1];
    const float* tang = P.p[lvl * 4 + 2];
    const float* scls = P.p[20 + lvl * 4 + 0];
    const float* sbox = P.p[20 + lvl * 4 + 1];
    const float* sang = P.p[20 + lvl * 4 + 2];
    const float* sctr = P.p[20 + lvl * 4 + 3];
    float siou = sigmoidf(sctr[idx]);
    float scl = 0.f;
    for (int c = 0; c < NCLS; c++) {
      float jc = sigmoidf(scls[c * hw + idx]) * siou;
      float ct = sel ? sigmoidf(tcls[c * hw + idx]) : 0.f;
      float p = jc;
      if (p < 1e-12f) p = 1e-12f;
      float pu = 1.f - 1e-12f;
      if (p > pu) p = pu;
      float bce = -(ct * logf(p) + (1.f - ct) * log1pf(-p));
      float d = fabsf(jc - ct);
      scl += bce * d * d;
    }
    v0 = scl;
    float lw = lp ? ctmax : 0.f;
    // loc target: hn-aggregated overrides, else raw teacher box for positives, else 0
    float tgt[5];
    if (hf) {
#pragma unroll
      for (int k = 0; k < 5; k++) tgt[k] = g_loc_targets[n * 5 + k];
    } else if (pm) {
      tgt[0] = tbox[idx]; tgt[1] = tbox[hw + idx];
      tgt[2] = tbox[2 * hw + idx]; tgt[3] = tbox[3 * hw + idx];
      tgt[4] = tang[idx];
    } else {
#pragma unroll
      for (int k = 0; k < 5; k++) tgt[k] = 0.f;
    }
    float sb = 0.f;
#pragma unroll
    for (int k = 0; k < 5; k++) {
      float sv = (k < 4) ? sbox[k * hw + idx] : sang[idx];
      float d = fabsf(sv - tgt[k]);
      sb += (d < 1.f) ? 0.5f * d * d : d - 0.5f;
    }
    v1 = sb * lw;
    v2 = 0.f;
    if (lp) {
      float p = siou;
      if (p < 1e-12f) p = 1e-12f;
      float pu = 1.f - 1e-12f;
      if (p > pu) p = pu;
      float ti = g_sig_tiou[n];
      v2 = -(ti * logf(p) + (1.f - ti) * log1pf(-p));
    }
    v3 = pm ? ctmax : 0.f;   // cls_avg
    v4 = lw;                 // loc_avg
    v5 = lp ? 1.f : 0.f;     // iou_avg
  }
  __shared__ float red[256][6];
  red[tid][0] = v0; red[tid][1] = v1; red[tid][2] = v2;
  red[tid][3] = v3; red[tid][4] = v4; red[tid][5] = v5;
  __syncthreads();
  for (int st = 128; st > 0; st >>= 1) {
    if (tid < st)
#pragma unroll
      for (int k = 0; k < 6; k++) red[tid][k] += red[tid + st][k];
    __syncthreads();
  }
  if (tid == 0)
#pragma unroll
    for (int k = 0; k < 6; k++) g_partials[blockIdx.x * 6 + k] = red[0][k];
}

// ---------------- kernel 11: final reduce ----------------
__global__ __launch_bounds__(256) void k_final(float* out) {
  int tid = threadIdx.x;
  float a[6] = {0,0,0,0,0,0};
  for (int b = tid; b < NBLK; b += 256)
#pragma unroll
    for (int k = 0; k < 6; k++) a[k] += g_partials[b * 6 + k];
  __shared__ float red[256][6];
#pragma unroll
  for (int k = 0; k < 6; k++) red[tid][k] = a[k];
  __syncthreads();
  for (int st = 128; st > 0; st >>= 1) {
    if (tid < st)
#pragma unroll
      for (int k = 0; k < 6; k++) red[tid][k] += red[tid + st][k];
    __syncthreads();
  }
  if (tid == 0) {
    out[0] = red[0][0] / fmaxf(red[0][3], 1e-8f);
    out[1] = red[0][1] / fmaxf(red[0][4], 1e-8f);
    out[2] = red[0][2] / fmaxf(red[0][5], 1.f);
  }
}

extern "C" void kernel_launch(void* const* d_in, const int* in_sizes, int n_in,
                              void* d_out, int out_size, void* d_ws, size_t ws_size,
                              hipStream_t stream) {
  (void)in_sizes; (void)n_in; (void)out_size; (void)d_ws; (void)ws_size;
  InPtrs P;
  for (int i = 0; i < 40; i++) P.p[i] = (const float*)d_in[i];
  k_prep<<<NBLK, 256, 0, stream>>>(P);
  k_thresh<<<1, 512, 0, stream>>>();
  k_mask<<<NBLK, 256, 0, stream>>>();
  k_scan<<<1, 512, 0, stream>>>();
  k_compact<<<NBLK, 256, 0, stream>>>();
  k_select<<<1, 1024, 0, stream>>>();
  k_decode<<<(KPOS + KHN + 255) / 256, 256, 0, stream>>>(P);
  k_iou<<<KHN, 256, 0, stream>>>();
  k_scatter<<<KHN / 256, 256, 0, stream>>>();
  k_loss<<<NBLK, 256, 0, stream>>>(P);
  k_final<<<1, 256, 0, stream>>>((float*)d_out);
}

// Round 3
// 59.301 us; speedup vs baseline: 5.5725x; 1.4683x over previous
//
#include <hip/hip_runtime.h>
#include <math.h>

#define NPTS 87296
#define NCLS 16
#define KPOS 256
#define KHN  2048
#define NBLK 341            // NPTS / 256 exactly
#define CAP  4096           // compacted-candidate capacity (slow path beyond)
#define PI_F   3.14159265358979323846f
#define HPI_F  1.57079632679489661923f

struct InPtrs { const float* p[40]; };
// input index = pre*20 + lvl*4 + {cls:0, box:1, ang:2, ctr:3}; pre: t=0, s=1

// ---------------- persistent device scratch (rewritten every call) ----------------
__device__ float g_max_vals[NPTS];
__device__ float g_sig_tiou[NPTS];
__device__ float g_sig_cls_max[NPTS];
__device__ int   g_class_ind[NPTS];
__device__ int   g_pos_mask[NPTS];
__device__ int   g_hn_mask[NPTS];
__device__ int   g_hnflag[NPTS];          // 1 = loc target overridden by aggregated hn
__device__ float g_loc_targets[NPTS * 5]; // only hn slots are written/read
__device__ float g_bsum[NBLK];
__device__ float g_bsumsq[NBLK];
__device__ int   g_bcnt[NBLK];
__device__ int   g_bpos[NBLK];
__device__ int   g_bhn[NBLK];
__device__ int   g_total_pos;
__device__ int   g_total_hn;
__device__ int   g_fallback;
__device__ int   g_pos_cand[CAP];
__device__ int   g_hn_cand[CAP];
__device__ int   g_pidx[KPOS];
__device__ int   g_pvalid[KPOS];
__device__ float g_pv[KPOS];
__device__ int   g_hidx[KHN];
__device__ int   g_hvalid[KHN];
__device__ float g_pos_bbox[KPOS * 5];
__device__ float g_pos_cor[KPOS * 8];
__device__ float g_pos_area[KPOS];
__device__ float g_pos_scale[KPOS];
__device__ int   g_pos_class[KPOS];
__device__ float g_hn_px[KHN];
__device__ float g_hn_py[KHN];
__device__ float g_hn_cor[KHN * 8];
__device__ float g_hn_area[KHN];
__device__ float g_hn_scale[KHN];
__device__ int   g_hn_class[KHN];
__device__ float g_partials[NBLK * 6];

// ---------------- helpers ----------------
__device__ __forceinline__ float sigmoidf(float x) {
  if (x >= 0.f) return 1.f / (1.f + expf(-x));
  float e = expf(x);
  return e / (1.f + e);
}
__device__ __forceinline__ float crs(float ax, float ay, float bx, float by) {
  return ax * by - ay * bx;
}
__device__ __forceinline__ float mod_pos(float x, float y) {
  float r = fmodf(x, y);
  if (r < 0.f) r += y;
  return r;
}
__device__ __forceinline__ void point_info(int n, int& lvl, int& idx, int& hw,
                                           float& px, float& py) {
  int off, wsh; float stride;
  if (n < 65536)      { lvl = 0; off = 0;     wsh = 8; stride = 8.f;   hw = 65536; }
  else if (n < 81920) { lvl = 1; off = 65536; wsh = 7; stride = 16.f;  hw = 16384; }
  else if (n < 86016) { lvl = 2; off = 81920; wsh = 6; stride = 32.f;  hw = 4096; }
  else if (n < 87040) { lvl = 3; off = 86016; wsh = 5; stride = 64.f;  hw = 1024; }
  else                { lvl = 4; off = 87040; wsh = 4; stride = 128.f; hw = 256; }
  idx = n - off;
  int y = idx >> wsh, x = idx & ((1 << wsh) - 1);
  px = ((float)x + 0.5f) * stride;
  py = ((float)y + 0.5f) * stride;
}

// ---------------- kernel 1: per-point teacher stats + mean/var partials ----------------
__global__ __launch_bounds__(256) void k_prep(InPtrs P) {
  int tid = threadIdx.x;
  int n = blockIdx.x * 256 + tid;
  int lvl, idx, hw; float px, py;
  point_info(n, lvl, idx, hw, px, py);
  const float* cls = P.p[lvl * 4 + 0];
  const float* ctr = P.p[lvl * 4 + 3];
  float stiou = sigmoidf(ctr[idx]);
  float mv = -1.f, scm = 0.f; int ci = 0;
  for (int c = 0; c < NCLS; c++) {
    float sc = sigmoidf(cls[c * hw + idx]);
    if (sc > scm) scm = sc;
    float j = sc * stiou;
    if (j > mv) { mv = j; ci = c; }
  }
  g_max_vals[n] = mv;
  g_class_ind[n] = ci;
  g_sig_tiou[n] = stiou;
  g_sig_cls_max[n] = scm;
  g_hnflag[n] = 0;
  float isc = (mv >= 0.1f) ? 1.f : 0.f;
  __shared__ float r0[256], r1[256], r2[256];
  r0[tid] = isc; r1[tid] = isc * mv; r2[tid] = isc * mv * mv;
  __syncthreads();
  for (int st = 128; st > 0; st >>= 1) {
    if (tid < st) { r0[tid] += r0[tid + st]; r1[tid] += r1[tid + st]; r2[tid] += r2[tid + st]; }
    __syncthreads();
  }
  if (tid == 0) {
    g_bcnt[blockIdx.x] = (int)r0[0];
    g_bsum[blockIdx.x] = r1[0];
    g_bsumsq[blockIdx.x] = r2[0];
  }
}

// ---------------- kernel 2: threshold (redundant per block) + masks + counts ----------------
__global__ __launch_bounds__(256) void k_mask() {
  int tid = threadIdx.x;
  __shared__ float s1[256], s2[256];
  __shared__ int s0[256];
  int c = 0; float s = 0.f, q = 0.f;
  for (int i = tid; i < NBLK; i += 256) { c += g_bcnt[i]; s += g_bsum[i]; q += g_bsumsq[i]; }
  s0[tid] = c; s1[tid] = s; s2[tid] = q; __syncthreads();
  for (int st = 128; st > 0; st >>= 1) {
    if (tid < st) { s0[tid] += s0[tid + st]; s1[tid] += s1[tid + st]; s2[tid] += s2[tid + st]; }
    __syncthreads();
  }
  int nc = s0[0]; float sum = s1[0], sumsq = s2[0];
  float mean = sum / (float)(nc > 1 ? nc : 1);
  float E = sumsq - 2.f * mean * sum + (float)nc * mean * mean;
  if (E < 0.f) E = 0.f;
  float var = E / (float)((nc - 1) > 1 ? (nc - 1) : 1);
  float th = fminf(mean + sqrtf(var), 0.4f);
  if (nc == 0) th = __int_as_float(0x7f800000);  // +inf

  int n = blockIdx.x * 256 + tid;
  float v = g_max_vals[n];
  int pm = (v >= th) ? 1 : 0;
  int hm = (v >= 0.1f && v < th) ? 1 : 0;
  g_pos_mask[n] = pm; g_hn_mask[n] = hm;
  __syncthreads();
  __shared__ int t0[256], t1[256];
  t0[tid] = pm; t1[tid] = hm; __syncthreads();
  for (int st = 128; st > 0; st >>= 1) {
    if (tid < st) { t0[tid] += t0[tid + st]; t1[tid] += t1[tid + st]; }
    __syncthreads();
  }
  if (tid == 0) { g_bpos[blockIdx.x] = t0[0]; g_bhn[blockIdx.x] = t1[0]; }
}

// ---------------- kernel 3: compaction with folded scan + totals ----------------
__global__ __launch_bounds__(256) void k_compact() {
  int tid = threadIdx.x, b = blockIdx.x;
  __shared__ int r0[256], r1[256];
  // totals (all blocks compute; block 0 writes)
  int cp = 0, ch = 0;
  for (int i = tid; i < NBLK; i += 256) { cp += g_bpos[i]; ch += g_bhn[i]; }
  r0[tid] = cp; r1[tid] = ch; __syncthreads();
  for (int st = 128; st > 0; st >>= 1) {
    if (tid < st) { r0[tid] += r0[tid + st]; r1[tid] += r1[tid + st]; }
    __syncthreads();
  }
  if (b == 0 && tid == 0) {
    g_total_pos = r0[0]; g_total_hn = r1[0];
    g_fallback = (r0[0] == 0) ? 1 : 0;
  }
  __syncthreads();
  // this block's exclusive offset
  cp = 0; ch = 0;
  for (int i = tid; i < b; i += 256) { cp += g_bpos[i]; ch += g_bhn[i]; }
  r0[tid] = cp; r1[tid] = ch; __syncthreads();
  for (int st = 128; st > 0; st >>= 1) {
    if (tid < st) { r0[tid] += r0[tid + st]; r1[tid] += r1[tid + st]; }
    __syncthreads();
  }
  int poff = r0[0], hoff = r1[0];
  __syncthreads();
  // in-block inclusive scan of masks
  int n = b * 256 + tid;
  int pm = g_pos_mask[n], hm = g_hn_mask[n];
  r0[tid] = pm; r1[tid] = hm; __syncthreads();
  for (int off = 1; off < 256; off <<= 1) {
    int ap = (tid >= off) ? r0[tid - off] : 0;
    int ah = (tid >= off) ? r1[tid - off] : 0;
    __syncthreads();
    r0[tid] += ap; r1[tid] += ah;
    __syncthreads();
  }
  if (pm) { int o = poff + r0[tid] - pm; if (o < CAP) g_pos_cand[o] = n; }
  if (hm) { int o = hoff + r1[tid] - hm; if (o < CAP) g_hn_cand[o] = n; }
}

// ---------------- radix select paths (rare) ----------------
#define MASK_ALL 0
#define MASK_POS 1
#define MASK_HN  2
__device__ __forceinline__ int sel_mask(int mode, int n) {
  return mode == MASK_ALL ? 1 : (mode == MASK_POS ? g_pos_mask[n] : g_hn_mask[n]);
}

__device__ void radix_select_mask(int mode, int K, int* out_idx, int* out_valid, float* out_val,
                                  int* hist, int* scan_a, int* scan_b, int* sh) {
  int tid = threadIdx.x;
  int c = 0;
  for (int n = tid; n < NPTS; n += 1024) if (sel_mask(mode, n)) c++;
  scan_a[tid] = c; __syncthreads();
  for (int st = 512; st > 0; st >>= 1) {
    if (tid < st) scan_a[tid] += scan_a[tid + st];
    __syncthreads();
  }
  int total = scan_a[0];
  __syncthreads();

  unsigned kth = 0u;
  if (total > K) {
    unsigned prefix = 0; int rem = K;
    for (int pass = 0; pass < 4; pass++) {
      int shift = 24 - 8 * pass;
      if (tid < 256) hist[tid] = 0;
      __syncthreads();
      for (int n = tid; n < NPTS; n += 1024) {
        if (sel_mask(mode, n)) {
          unsigned k = __float_as_uint(g_max_vals[n]);
          if (pass == 0 || ((k >> (shift + 8)) == prefix))
            atomicAdd(&hist[(k >> shift) & 255], 1);
        }
      }
      __syncthreads();
      if (tid == 0) {
        int cum = 0, b = 255;
        for (; b > 0; b--) {
          if (cum + hist[b] >= rem) break;
          cum += hist[b];
        }
        sh[0] = (int)((prefix << 8) | (unsigned)b);
        sh[1] = rem - cum;
      }
      __syncthreads();
      prefix = (unsigned)sh[0]; rem = sh[1];
      __syncthreads();
    }
    kth = prefix;
  }

  const int chunk = (NPTS + 1023) / 1024;
  int start = tid * chunk; if (start > NPTS) start = NPTS;
  int end = start + chunk; if (end > NPTS) end = NPTS;
  int cgt = 0, ceq = 0;
  for (int n = start; n < end; n++) {
    if (sel_mask(mode, n)) {
      unsigned k = __float_as_uint(g_max_vals[n]);
      if (k > kth) cgt++;
      else if (k == kth) ceq++;
    }
  }
  scan_a[tid] = cgt; scan_b[tid] = ceq; __syncthreads();
  if (tid == 0) {
    int ag = 0, ae = 0;
    for (int i = 0; i < 1024; i++) {
      int tg = scan_a[i], te = scan_b[i];
      scan_a[i] = ag; scan_b[i] = ae;
      ag += tg; ae += te;
    }
    sh[0] = ag; sh[1] = ae;
  }
  __syncthreads();
  int cnt_gt = sh[0], cnt_eq = sh[1];
  int og = scan_a[tid], oe = cnt_gt + scan_b[tid];
  for (int n = start; n < end; n++) {
    if (sel_mask(mode, n)) {
      unsigned k = __float_as_uint(g_max_vals[n]);
      if (k > kth) {
        out_idx[og] = n; out_valid[og] = 1;
        if (out_val) out_val[og] = g_max_vals[n];
        og++;
      } else if (k == kth) {
        if (oe < K) {
          out_idx[oe] = n; out_valid[oe] = 1;
          if (out_val) out_val[oe] = g_max_vals[n];
        }
        oe++;
      }
    }
  }
  int kmc = K - cnt_gt;
  int used = cnt_gt + (cnt_eq < kmc ? cnt_eq : kmc);
  __syncthreads();
  for (int i = used + tid; i < K; i += 1024) {
    out_idx[i] = 0; out_valid[i] = 0;
    if (out_val) out_val[i] = -1.f;
  }
  __syncthreads();
}

__device__ void radix_select_list(const int* list, int count, int K,
                                  int* out_idx, int* out_valid, float* out_val,
                                  int* hist, int* scan_a, int* scan_b, int* sh) {
  // requires count > K
  int tid = threadIdx.x;
  unsigned prefix = 0; int rem = K;
  for (int pass = 0; pass < 4; pass++) {
    int shift = 24 - 8 * pass;
    if (tid < 256) hist[tid] = 0;
    __syncthreads();
    for (int i = tid; i < count; i += 1024) {
      unsigned k = __float_as_uint(g_max_vals[list[i]]);
      if (pass == 0 || ((k >> (shift + 8)) == prefix))
        atomicAdd(&hist[(k >> shift) & 255], 1);
    }
    __syncthreads();
    if (tid == 0) {
      int cum = 0, b = 255;
      for (; b > 0; b--) {
        if (cum + hist[b] >= rem) break;
        cum += hist[b];
      }
      sh[0] = (int)((prefix << 8) | (unsigned)b);
      sh[1] = rem - cum;
    }
    __syncthreads();
    prefix = (unsigned)sh[0]; rem = sh[1];
    __syncthreads();
  }
  unsigned kth = prefix;
  int chunk = (count + 1023) / 1024;
  int start = tid * chunk; if (start > count) start = count;
  int end = start + chunk; if (end > count) end = count;
  int cgt = 0, ceq = 0;
  for (int i = start; i < end; i++) {
    unsigned k = __float_as_uint(g_max_vals[list[i]]);
    if (k > kth) cgt++;
    else if (k == kth) ceq++;
  }
  scan_a[tid] = cgt; scan_b[tid] = ceq; __syncthreads();
  if (tid == 0) {
    int ag = 0, ae = 0;
    for (int i = 0; i < 1024; i++) {
      int tg = scan_a[i], te = scan_b[i];
      scan_a[i] = ag; scan_b[i] = ae;
      ag += tg; ae += te;
    }
    sh[0] = ag;
  }
  __syncthreads();
  int cnt_gt = sh[0];
  int og = scan_a[tid], oe = cnt_gt + scan_b[tid];
  for (int i = start; i < end; i++) {
    int n = list[i];
    unsigned k = __float_as_uint(g_max_vals[n]);
    if (k > kth) {
      out_idx[og] = n; out_valid[og] = 1;
      if (out_val) out_val[og] = g_max_vals[n];
      og++;
    } else if (k == kth) {
      if (oe < K) {
        out_idx[oe] = n; out_valid[oe] = 1;
        if (out_val) out_val[oe] = g_max_vals[n];
      }
      oe++;
    }
  }
  __syncthreads();
}

// ---------------- kernel 4: selection (fast copy path; radix only when needed) ----------------
__global__ __launch_bounds__(1024) void k_select() {
  int tid = threadIdx.x;
  __shared__ int hist[256], scan_a[1024], scan_b[1024], sh_i[4];
  int fallback = g_fallback;
  int tp = g_total_pos, thn = g_total_hn;

  if (!fallback && tp <= KPOS) {
    for (int i = tid; i < KPOS; i += 1024) {
      if (i < tp) {
        int n = g_pos_cand[i];
        g_pidx[i] = n; g_pvalid[i] = 1; g_pv[i] = g_max_vals[n];
      } else { g_pidx[i] = 0; g_pvalid[i] = 0; g_pv[i] = -1.f; }
    }
  } else if (!fallback && tp <= CAP) {
    radix_select_list(g_pos_cand, tp, KPOS, g_pidx, g_pvalid, g_pv, hist, scan_a, scan_b, sh_i);
  } else if (!fallback) {
    radix_select_mask(MASK_POS, KPOS, g_pidx, g_pvalid, g_pv, hist, scan_a, scan_b, sh_i);
  } else {
    radix_select_mask(MASK_ALL, 10, g_pidx, g_pvalid, g_pv, hist, scan_a, scan_b, sh_i);
    for (int i = tid; i < 10; i += 1024)
      if (g_pvalid[i]) g_pos_mask[g_pidx[i]] = 1;
    for (int i = 10 + tid; i < KPOS; i += 1024) {
      g_pidx[i] = 0; g_pvalid[i] = 0; g_pv[i] = -1.f;
    }
  }
  __syncthreads();

  if (thn <= KHN) {
    for (int i = tid; i < KHN; i += 1024) {
      if (i < thn) { g_hidx[i] = g_hn_cand[i]; g_hvalid[i] = 1; }
      else { g_hidx[i] = 0; g_hvalid[i] = 0; }
    }
  } else if (thn <= CAP) {
    radix_select_list(g_hn_cand, thn, KHN, g_hidx, g_hvalid, (float*)0, hist, scan_a, scan_b, sh_i);
  } else {
    radix_select_mask(MASK_HN, KHN, g_hidx, g_hvalid, (float*)0, hist, scan_a, scan_b, sh_i);
  }
}

// ---------------- kernel 5: decode selected boxes ----------------
__device__ void decode_box(int n, const InPtrs& P, float* bb, float* cor,
                           float& area, float& scale, int& cls_out,
                           float* opx, float* opy) {
  int lvl, idx, hw; float px, py;
  point_info(n, lvl, idx, hw, px, py);
  const float* box = P.p[lvl * 4 + 1];
  const float* ang = P.p[lvl * 4 + 2];
  float l = box[idx], t = box[hw + idx], r = box[2 * hw + idx], b = box[3 * hw + idx];
  float a = ang[idx];
  float ca = cosf(a), sa = sinf(a);
  float w = l + r, h = t + b;
  float oxl = (r - l) * 0.5f, oyl = (b - t) * 0.5f;
  float ox = ca * oxl - sa * oyl;
  float oy = sa * oxl + ca * oyl;
  float an = mod_pos(a + HPI_F, PI_F) - HPI_F;
  float cx = px + ox, cy = py + oy;
  bb[0] = cx; bb[1] = cy; bb[2] = w; bb[3] = h; bb[4] = an;
  float c2 = cosf(an), s2 = sinf(an);
  const float dxs[4] = {-0.5f, 0.5f, 0.5f, -0.5f};
  const float dys[4] = {-0.5f, -0.5f, 0.5f, 0.5f};
#pragma unroll
  for (int k = 0; k < 4; k++) {
    float dx = dxs[k] * w, dy = dys[k] * h;
    cor[2 * k]     = cx + dx * c2 - dy * s2;
    cor[2 * k + 1] = cy + dx * s2 + dy * c2;
  }
  area = fabsf(w * h);
  scale = (float)lvl;
  cls_out = g_class_ind[n];
  if (opx) { *opx = px; *opy = py; }
}

__global__ __launch_bounds__(256) void k_decode(InPtrs P) {
  int i = blockIdx.x * 256 + threadIdx.x;
  if (i < KPOS) {
    float bb[5] = {0,0,0,0,0}, cor[8] = {0,0,0,0,0,0,0,0};
    float ar = 0.f, sc = 0.f; int cl = 0;
    if (g_pvalid[i]) decode_box(g_pidx[i], P, bb, cor, ar, sc, cl, (float*)0, (float*)0);
#pragma unroll
    for (int k = 0; k < 5; k++) g_pos_bbox[i * 5 + k] = bb[k];
#pragma unroll
    for (int k = 0; k < 8; k++) g_pos_cor[i * 8 + k] = cor[k];
    g_pos_area[i] = ar; g_pos_scale[i] = sc; g_pos_class[i] = cl;
  } else if (i < KPOS + KHN) {
    int h = i - KPOS;
    float bb[5] = {0,0,0,0,0}, cor[8] = {0,0,0,0,0,0,0,0};
    float ar = 0.f, sc = 0.f, px = 0.f, py = 0.f; int cl = 0;
    if (g_hvalid[h]) decode_box(g_hidx[h], P, bb, cor, ar, sc, cl, &px, &py);
#pragma unroll
    for (int k = 0; k < 8; k++) g_hn_cor[h * 8 + k] = cor[k];
    g_hn_area[h] = ar; g_hn_scale[h] = sc; g_hn_class[h] = cl;
    g_hn_px[h] = px; g_hn_py[h] = py;
  }
}

// ---------------- convex quad intersection — fully register-resident ----------------
// Bitonic compare-exchange pass over 32 slots; all indices compile-time.
#define BPASS(KK, JJ)                                                      \
  _Pragma("unroll")                                                        \
  for (int i = 0; i < 32; i++) {                                           \
    int l = i ^ (JJ);                                                      \
    if (l > i) {                                                           \
      bool up = ((i & (KK)) == 0);                                         \
      float aa = sa_[i], ab = sa_[l];                                      \
      bool sw = up ? (aa > ab) : (aa < ab);                                \
      sa_[i] = sw ? ab : aa; sa_[l] = sw ? aa : ab;                        \
      float xi = sx_[i], xl = sx_[l];                                      \
      sx_[i] = sw ? xl : xi; sx_[l] = sw ? xi : xl;                        \
      float yi = sy_[i], yl = sy_[l];                                      \
      sy_[i] = sw ? yl : yi; sy_[l] = sw ? yi : yl;                        \
    }                                                                      \
  }

__device__ float inter_area(const float* __restrict__ A, const float* __restrict__ B) {
  float ax[4], ay[4], bx[4], by[4];
#pragma unroll
  for (int i = 0; i < 4; i++) {
    ax[i] = A[2 * i]; ay[i] = A[2 * i + 1];
    bx[i] = B[2 * i]; by[i] = B[2 * i + 1];
  }
  float dax[4], day[4], dbx[4], dby[4];
#pragma unroll
  for (int i = 0; i < 4; i++) {
    int i1 = (i + 1) & 3;
    dax[i] = ax[i1] - ax[i]; day[i] = ay[i1] - ay[i];
    dbx[i] = bx[i1] - bx[i]; dby[i] = by[i1] - by[i];
  }
  float px[24], py[24]; bool val[24];
#pragma unroll
  for (int i = 0; i < 4; i++) {
#pragma unroll
    for (int j = 0; j < 4; j++) {
      float dx = bx[j] - ax[i], dy = by[j] - ay[i];
      float den = crs(dax[i], day[i], dbx[j], dby[j]);
      float ad = fabsf(den);
      float ds = (ad < 1e-10f) ? 1.0f : den;
      float t = crs(dx, dy, dbx[j], dby[j]) / ds;
      float u = crs(dx, dy, dax[i], day[i]) / ds;
      bool ok = (ad > 1e-10f) & (t >= 0.f) & (t <= 1.f) & (u >= 0.f) & (u <= 1.f);
      int k = i * 4 + j;
      px[k] = ax[i] + t * dax[i];
      py[k] = ay[i] + t * day[i];
      val[k] = ok;
    }
  }
#pragma unroll
  for (int i = 0; i < 4; i++) {   // corners of A inside B
    bool ge = true, le = true;
#pragma unroll
    for (int j = 0; j < 4; j++) {
      float s = crs(dbx[j], dby[j], ax[i] - bx[j], ay[i] - by[j]);
      ge = ge && (s >= -1e-9f);
      le = le && (s <= 1e-9f);
    }
    val[16 + i] = ge || le; px[16 + i] = ax[i]; py[16 + i] = ay[i];
  }
#pragma unroll
  for (int j = 0; j < 4; j++) {   // corners of B inside A
    bool ge = true, le = true;
#pragma unroll
    for (int i = 0; i < 4; i++) {
      float s = crs(dax[i], day[i], bx[j] - ax[i], by[j] - ay[i]);
      ge = ge && (s >= -1e-9f);
      le = le && (s <= 1e-9f);
    }
    val[20 + j] = ge || le; px[20 + j] = bx[j]; py[20 + j] = by[j];
  }
  int n = 0; float sx = 0.f, sy = 0.f;
#pragma unroll
  for (int k = 0; k < 24; k++) if (val[k]) { n++; sx += px[k]; sy += py[k]; }
  float dn = (float)(n > 1 ? n : 1);
  float cx = sx / dn, cy = sy / dn;

  // sort slots: 24 real (invalid collapsed to centroid) + 8 +INF dummies.
  // Non-stable network OK: angle ties occur only among identical centroid
  // points whose shoelace terms are exactly zero.
  float sa_[32], sx_[32], sy_[32];
#pragma unroll
  for (int k = 0; k < 24; k++) {
    float X = val[k] ? px[k] : cx;
    float Y = val[k] ? py[k] : cy;
    sx_[k] = X; sy_[k] = Y;
    sa_[k] = atan2f(Y - cy, X - cx);
  }
#pragma unroll
  for (int k = 24; k < 32; k++) {
    sa_[k] = __int_as_float(0x7f800000);  // +inf
    sx_[k] = cx; sy_[k] = cy;
  }
  BPASS(2, 1)
  BPASS(4, 2)  BPASS(4, 1)
  BPASS(8, 4)  BPASS(8, 2)  BPASS(8, 1)
  BPASS(16, 8) BPASS(16, 4) BPASS(16, 2) BPASS(16, 1)
  BPASS(32, 16) BPASS(32, 8) BPASS(32, 4) BPASS(32, 2) BPASS(32, 1)

  float s2 = 0.f;
#pragma unroll
  for (int k = 0; k < 24; k++) {
    int k1 = (k + 1) % 24;
    s2 += crs(sx_[k] - cx, sy_[k] - cy, sx_[k1] - cx, sy_[k1] - cy);
  }
  float area = 0.5f * fabsf(s2);
  return (n >= 3) ? area : 0.f;
}

// ---------------- kernel 6: IoU + aggregation + inline scatter ----------------
__global__ __launch_bounds__(256) void k_iou() {
  int h = blockIdx.x;
  int j = threadIdx.x;
  if (!g_hvalid[h]) return;
  float wsum = 0.f, wb[5] = {0,0,0,0,0}, anyv = 0.f;
  if (g_pvalid[j]) {
    bool valid = (g_pos_class[j] == g_hn_class[h]) &&
                 (fabsf(g_pos_scale[j] - g_hn_scale[h]) <= 1.0f);
    if (valid) {
      float cx = g_pos_bbox[j * 5 + 0], cy = g_pos_bbox[j * 5 + 1];
      float bw = g_pos_bbox[j * 5 + 2], bh = g_pos_bbox[j * 5 + 3];
      float an = g_pos_bbox[j * 5 + 4];
      float ca = cosf(an), sa = sinf(an);
      float dx = g_hn_px[h] - cx, dy = g_hn_py[h] - cy;
      float ox = ca * dx + sa * dy, oy = -sa * dx + ca * dy;
      float m = fminf(fminf(bw * 0.5f + ox, bw * 0.5f - ox),
                      fminf(bh * 0.5f + oy, bh * 0.5f - oy));
      valid = (m > 0.f);
    }
    if (valid) {
      float inter = inter_area(&g_hn_cor[h * 8], &g_pos_cor[j * 8]);
      float iou = inter / (g_hn_area[h] + g_pos_area[j] - inter + 1e-8f);
      valid = (iou >= 0.6f);
    }
    if (valid) {
      anyv = 1.f;
      float w = g_pv[j];
      wsum = w;
#pragma unroll
      for (int k = 0; k < 5; k++) wb[k] = w * g_pos_bbox[j * 5 + k];
    }
  }
  __shared__ float red[7][256];   // lane-major: conflict-free
  red[0][j] = wsum;
#pragma unroll
  for (int k = 0; k < 5; k++) red[1 + k][j] = wb[k];
  red[6][j] = anyv;
  __syncthreads();
  for (int st = 128; st > 0; st >>= 1) {
    if (j < st)
#pragma unroll
      for (int k = 0; k < 7; k++) red[k][j] += red[k][j + st];
    __syncthreads();
  }
  if (j == 0 && red[6][0] > 0.f) {
    float inv = 1.f / fmaxf(red[0][0], 1e-8f);
    float bb[5];
#pragma unroll
    for (int k = 0; k < 5; k++) bb[k] = red[1 + k][0] * inv;
    float ca = cosf(bb[4]), sa = sinf(bb[4]);
    float dx = g_hn_px[h] - bb[0], dy = g_hn_py[h] - bb[1];
    float ox = ca * dx + sa * dy, oy = -sa * dx + ca * dy;
    int n = g_hidx[h];
    g_loc_targets[n * 5 + 0] = bb[2] * 0.5f + ox;
    g_loc_targets[n * 5 + 1] = bb[3] * 0.5f + oy;
    g_loc_targets[n * 5 + 2] = bb[2] * 0.5f - ox;
    g_loc_targets[n * 5 + 3] = bb[3] * 0.5f - oy;
    g_loc_targets[n * 5 + 4] = bb[4];
    g_hnflag[n] = 1;
  }
}

// ---------------- kernel 7: per-point losses -> block partials ----------------
__global__ __launch_bounds__(256) void k_loss(InPtrs P) {
  int tid = threadIdx.x;
  int n = blockIdx.x * 256 + tid;
  float v0, v1, v2, v3, v4, v5;
  {
    int lvl, idx, hw; float px, py;
    point_info(n, lvl, idx, hw, px, py);
    int pm = g_pos_mask[n], hm = g_hn_mask[n], hf = g_hnflag[n];
    int sel = pm | hm;
    bool lp = (pm | hf) != 0;
    float ctmax = sel ? g_sig_cls_max[n] : 0.f;
    const float* tcls = P.p[lvl * 4 + 0];
    const float* tbox = P.p[lvl * 4 + 1];
    const float* tang = P.p[lvl * 4 + 2];
    const float* scls = P.p[20 + lvl * 4 + 0];
    const float* sbox = P.p[20 + lvl * 4 + 1];
    const float* sang = P.p[20 + lvl * 4 + 2];
    const float* sctr = P.p[20 + lvl * 4 + 3];
    float siou = sigmoidf(sctr[idx]);
    float scl = 0.f;
    for (int c = 0; c < NCLS; c++) {
      float jc = sigmoidf(scls[c * hw + idx]) * siou;
      float ct = sel ? sigmoidf(tcls[c * hw + idx]) : 0.f;
      float p = jc;
      if (p < 1e-12f) p = 1e-12f;
      float pu = 1.f - 1e-12f;
      if (p > pu) p = pu;
      float bce = -(ct * logf(p) + (1.f - ct) * log1pf(-p));
      float d = fabsf(jc - ct);
      scl += bce * d * d;
    }
    v0 = scl;
    float lw = lp ? ctmax : 0.f;
    float tgt[5];
    if (hf) {
#pragma unroll
      for (int k = 0; k < 5; k++) tgt[k] = g_loc_targets[n * 5 + k];
    } else if (pm) {
      tgt[0] = tbox[idx]; tgt[1] = tbox[hw + idx];
      tgt[2] = tbox[2 * hw + idx]; tgt[3] = tbox[3 * hw + idx];
      tgt[4] = tang[idx];
    } else {
#pragma unroll
      for (int k = 0; k < 5; k++) tgt[k] = 0.f;
    }
    float sb = 0.f;
#pragma unroll
    for (int k = 0; k < 5; k++) {
      float sv = (k < 4) ? sbox[k * hw + idx] : sang[idx];
      float d = fabsf(sv - tgt[k]);
      sb += (d < 1.f) ? 0.5f * d * d : d - 0.5f;
    }
    v1 = sb * lw;
    v2 = 0.f;
    if (lp) {
      float p = siou;
      if (p < 1e-12f) p = 1e-12f;
      float pu = 1.f - 1e-12f;
      if (p > pu) p = pu;
      float ti = g_sig_tiou[n];
      v2 = -(ti * logf(p) + (1.f - ti) * log1pf(-p));
    }
    v3 = pm ? ctmax : 0.f;   // cls_avg
    v4 = lw;                 // loc_avg
    v5 = lp ? 1.f : 0.f;     // iou_avg
  }
  __shared__ float red[6][256];
  red[0][tid] = v0; red[1][tid] = v1; red[2][tid] = v2;
  red[3][tid] = v3; red[4][tid] = v4; red[5][tid] = v5;
  __syncthreads();
  for (int st = 128; st > 0; st >>= 1) {
    if (tid < st)
#pragma unroll
      for (int k = 0; k < 6; k++) red[k][tid] += red[k][tid + st];
    __syncthreads();
  }
  if (tid == 0)
#pragma unroll
    for (int k = 0; k < 6; k++) g_partials[blockIdx.x * 6 + k] = red[k][0];
}

// ---------------- kernel 8: final reduce ----------------
__global__ __launch_bounds__(256) void k_final(float* out) {
  int tid = threadIdx.x;
  float a[6] = {0,0,0,0,0,0};
  for (int b = tid; b < NBLK; b += 256)
#pragma unroll
    for (int k = 0; k < 6; k++) a[k] += g_partials[b * 6 + k];
  __shared__ float red[6][256];
#pragma unroll
  for (int k = 0; k < 6; k++) red[k][tid] = a[k];
  __syncthreads();
  for (int st = 128; st > 0; st >>= 1) {
    if (tid < st)
#pragma unroll
      for (int k = 0; k < 6; k++) red[k][tid] += red[k][tid + st];
    __syncthreads();
  }
  if (tid == 0) {
    out[0] = red[0][0] / fmaxf(red[3][0], 1e-8f);
    out[1] = red[1][0] / fmaxf(red[4][0], 1e-8f);
    out[2] = red[2][0] / fmaxf(red[5][0], 1.f);
  }
}

extern "C" void kernel_launch(void* const* d_in, const int* in_sizes, int n_in,
                              void* d_out, int out_size, void* d_ws, size_t ws_size,
                              hipStream_t stream) {
  (void)in_sizes; (void)n_in; (void)out_size; (void)d_ws; (void)ws_size;
  InPtrs P;
  for (int i = 0; i < 40; i++) P.p[i] = (const float*)d_in[i];
  k_prep<<<NBLK, 256, 0, stream>>>(P);
  k_mask<<<NBLK, 256, 0, stream>>>();
  k_compact<<<NBLK, 256, 0, stream>>>();
  k_select<<<1, 1024, 0, stream>>>();
  k_decode<<<(KPOS + KHN + 255) / 256, 256, 0, stream>>>(P);
  k_iou<<<KHN, 256, 0, stream>>>();
  k_loss<<<NBLK, 256, 0, stream>>>(P);
  k_final<<<1, 256, 0, stream>>>((float*)d_out);
}